// Round 4
// baseline (257.907 us; speedup 1.0000x reference)
//
#include <hip/hip_runtime.h>
#include <hip/hip_bf16.h>

// ---------- types ----------
typedef float f32x4 __attribute__((ext_vector_type(4)));
typedef int   v8i   __attribute__((ext_vector_type(8)));
typedef __attribute__((address_space(3))) unsigned int       lds_uint;
typedef __attribute__((address_space(1))) const unsigned int glb_uint;

// ---------- helpers ----------
__device__ __forceinline__ float tanh_fast(float x) {
    float e = __expf(-2.0f * fabsf(x));
    float r = (1.0f - e) / (1.0f + e);
    return copysignf(r, x);
}
__device__ __forceinline__ unsigned char f2fp8(float v) {
    return (unsigned char)(__builtin_amdgcn_cvt_pk_fp8_f32(v, 0.0f, 0, false) & 0xff);
}

// ---------- prep: x->fp8; proj W ->fp8(x16) T; r1/r2 ->fp8(x16) T; bias concat ----------
__global__ __launch_bounds__(256) void prep(
    const float* __restrict__ x,
    const float* __restrict__ theta_w, const float* __restrict__ phi_w,
    const float* __restrict__ psi_w,   const float* __restrict__ r1_w,
    const float* __restrict__ r2_w,
    const float* __restrict__ theta_b, const float* __restrict__ phi_b,
    const float* __restrict__ psi_b,
    unsigned char* __restrict__ xb8, unsigned char* __restrict__ wCat8T,
    unsigned char* __restrict__ r1T8, unsigned char* __restrict__ r2T8,
    float* __restrict__ bCat) {
    const int b = blockIdx.x, t = threadIdx.x;
    if (b < 8192) {                       // cast x -> fp8
        long i = ((long)b * 256 + t) * 4;
        float4 f = *(const float4*)(x + i);
        int w = __builtin_amdgcn_cvt_pk_fp8_f32(f.x, f.y, 0, false);
        w = __builtin_amdgcn_cvt_pk_fp8_f32(f.z, f.w, w, true);
        *(unsigned int*)(xb8 + i) = (unsigned int)w;
    } else if (b < 11264) {               // proj weights (512x512 each), x16, transposed
        const int sel = (b - 8192) >> 10;
        const int idx = ((b - 8192) & 1023) * 256 + t;
        const float* w = sel == 0 ? theta_w : (sel == 1 ? phi_w : psi_w);
        const int r = idx >> 9, c = idx & 511;
        wCat8T[(long)(sel * 512 + c) * 512 + r] = f2fp8(w[idx] * 16.0f);
    } else if (b < 11776) {               // r1 (512x256) -> fp8 x16 T
        const int idx = (b - 11264) * 256 + t;
        const int r = idx >> 8, c = idx & 255;
        r1T8[(long)c * 512 + r] = f2fp8(r1_w[idx] * 16.0f);
    } else if (b < 12288) {               // r2 (256x512) -> fp8 x16 T
        const int idx = (b - 11776) * 256 + t;
        const int r = idx >> 9, c = idx & 511;
        r2T8[(long)c * 256 + r] = f2fp8(r2_w[idx] * 16.0f);
    } else {                              // bias concat (1536)
        const int i = (b - 12288) * 256 + t;
        if (i < 1536)
            bCat[i] = i < 512 ? theta_b[i] : (i < 1024 ? phi_b[i - 512] : psi_b[i - 1024]);
    }
}

// ---------- fp8 GEMM: 128x128 tile, BK=128, dbuf counted-vmcnt ----------
// MODE 0 proj:  v=acc/16+bCat[col]; col<1024 -> fp8 out8/out8b (pitch 512);
//               col>=1024 -> V^T (dword stores: 4 l-consecutive rows packed)
// MODE 3 r1:    v=acc/16+bias; leaky 0.2; fp8 -> out8, pitch 256
// MODE 4 r2:    v=acc/16+bias; tanh; +resid; fp32 -> outF, ldc 512
template <int MODE>
__global__ __launch_bounds__(256) void gemm_fp8(
    const unsigned char* __restrict__ A,
    const unsigned char* __restrict__ Bt,
    const float* __restrict__ bias,
    const float* __restrict__ resid,
    unsigned char* __restrict__ out8,
    unsigned char* __restrict__ out8b,
    unsigned char* __restrict__ outV,
    float* __restrict__ outF,
    int K, int ldaB, int ldbB, int ldc, long sA, long sB, long sC) {
    __shared__ unsigned char As[2][128 * 128];
    __shared__ unsigned char Bs[2][128 * 128];

    const int tid  = threadIdx.x;
    const int lane = tid & 63, wave = tid >> 6;
    const int m16  = lane & 15, quad = lane >> 4;
    const int wm   = (wave >> 1) << 6, wn = (wave & 1) << 6;
    const int m0   = blockIdx.x << 7, n0 = blockIdx.y << 7;

    const int srow = lane >> 3;
    const int uswz = (lane & 7) ^ srow;

    const unsigned char* Abase = A  + (long)blockIdx.z * sA + (long)m0 * ldaB;
    const unsigned char* Bbase = Bt + (long)blockIdx.z * sB + (long)n0 * ldbB;
    const int stR = (wave << 5) + srow;
    const long gA0 = (long)stR * ldaB + (uswz << 4);
    const long gB0 = (long)stR * ldbB + (uswz << 4);

    // LDS 16B-unit u of row m holds true unit u^(m&7); lane's 32B at region
    // P = quad^((m&7)>>1), half order flips w/ m&1 -> 2x ds_read_b128, bank-optimal.
    const int s8  = m16 & 7;
    const int P   = quad ^ (s8 >> 1);
    const int cLo = (P << 1) + (s8 & 1);
    const int offLo = cLo << 4;
    const int offHi = (cLo ^ 1) << 4;

    f32x4 acc[4][4] = {};
    union F8 { v8i v; int4 q[2]; };

    auto STAGE = [&](int buf, int kk) {
#pragma unroll
        for (int i = 0; i < 4; ++i) {
            const unsigned char* gp = Abase + gA0 + (long)(i << 3) * ldaB + kk;
            unsigned char* lp = &As[buf][((wave << 5) + (i << 3)) << 7];
            __builtin_amdgcn_global_load_lds((glb_uint*)gp, (lds_uint*)lp, 16, 0, 0);
        }
#pragma unroll
        for (int i = 0; i < 4; ++i) {
            const unsigned char* gp = Bbase + gB0 + (long)(i << 3) * ldbB + kk;
            unsigned char* lp = &Bs[buf][((wave << 5) + (i << 3)) << 7];
            __builtin_amdgcn_global_load_lds((glb_uint*)gp, (lds_uint*)lp, 16, 0, 0);
        }
    };

    STAGE(0, 0);
    int cur = 0;
    for (int k0 = 0; k0 < K; k0 += 128) {
        if (k0 + 128 < K) {
            STAGE(cur ^ 1, k0 + 128);
            asm volatile("s_waitcnt vmcnt(8)" ::: "memory");
        } else {
            asm volatile("s_waitcnt vmcnt(0)" ::: "memory");
        }
        asm volatile("s_barrier" ::: "memory");

        const unsigned char* Ab = As[cur];
        const unsigned char* Bb = Bs[cur];
        F8 af[4], bg[4];
#pragma unroll
        for (int f = 0; f < 4; ++f) {
            const int m = wm + (f << 4) + m16;
            const int n = wn + (f << 4) + m16;
            af[f].q[0] = *(const int4*)&Ab[(m << 7) + offLo];
            af[f].q[1] = *(const int4*)&Ab[(m << 7) + offHi];
            bg[f].q[0] = *(const int4*)&Bb[(n << 7) + offLo];
            bg[f].q[1] = *(const int4*)&Bb[(n << 7) + offHi];
        }
#pragma unroll
        for (int fi = 0; fi < 4; ++fi)
#pragma unroll
            for (int fj = 0; fj < 4; ++fj)
                acc[fi][fj] = __builtin_amdgcn_mfma_scale_f32_16x16x128_f8f6f4(
                    af[fi].v, bg[fj].v, acc[fi][fj],
                    0, 0, 0, 127, 0, 127);

        asm volatile("s_waitcnt lgkmcnt(0)" ::: "memory");
        asm volatile("s_barrier" ::: "memory");
        cur ^= 1;
    }

    if (MODE == 0) {
        const int sel = n0 >> 9;
        if (sel < 2) {
            unsigned char* dst = sel == 0 ? out8 : out8b;
#pragma unroll
            for (int fj = 0; fj < 4; ++fj) {
                const int col = n0 + wn + (fj << 4) + m16;
                const int cb  = col & 511;
                const float bv = bias[col];
#pragma unroll
                for (int fi = 0; fi < 4; ++fi)
#pragma unroll
                    for (int r = 0; r < 4; ++r) {
                        const int row = m0 + wm + (fi << 4) + (quad << 2) + r;
                        dst[(long)row * 512 + cb] = f2fp8(acc[fi][fj][r] * 0.0625f + bv);
                    }
            }
        } else {                                    // V^T: pack 4 l-rows per dword
            const int z = m0 >> 11, l0 = (m0 & 2047) + wm + (quad << 2);
#pragma unroll
            for (int fj = 0; fj < 4; ++fj) {
                const int col = n0 + wn + (fj << 4) + m16;
                const int h   = col & 511;
                const float bv = bias[col];
#pragma unroll
                for (int fi = 0; fi < 4; ++fi) {
                    int w = __builtin_amdgcn_cvt_pk_fp8_f32(
                        acc[fi][fj][0] * 0.0625f + bv, acc[fi][fj][1] * 0.0625f + bv, 0, false);
                    w = __builtin_amdgcn_cvt_pk_fp8_f32(
                        acc[fi][fj][2] * 0.0625f + bv, acc[fi][fj][3] * 0.0625f + bv, w, true);
                    *(unsigned int*)(outV + ((long)z * 512 + h) * 2048 + l0 + (fi << 4)) =
                        (unsigned int)w;
                }
            }
        }
    } else {
#pragma unroll
        for (int fj = 0; fj < 4; ++fj) {
            const int col = n0 + wn + (fj << 4) + m16;
            const float bv = bias[col];
#pragma unroll
            for (int fi = 0; fi < 4; ++fi)
#pragma unroll
                for (int r = 0; r < 4; ++r) {
                    const int row = m0 + wm + (fi << 4) + (quad << 2) + r;
                    float v = acc[fi][fj][r] * 0.0625f + bv;
                    if (MODE == 3) {
                        v = v > 0.0f ? v : 0.2f * v;
                        out8[(long)row * 256 + col] = f2fp8(v);
                    } else {
                        const long idx = (long)row * ldc + col;
                        outF[idx] = tanh_fast(v) + resid[idx];
                    }
                }
        }
    }
}

// ---------- flash: fused S = phi@theta^T -> online softmax -> P@V ----------
// Block = 64 q-rows of batch z. 512 thr / 8 waves.
// S-phase wave split: (2 l-groups of 32) x (4 m-groups of 32); per-wave S frags 2x2.
// PV-phase:           (2 l-groups of 32) x (4 h-groups of 128); per-wave U frags 2x8.
// LDS: Q 32K + K dbuf 32K + V 64K + P 8K + stats 2K = 138 KB -> 1 block/CU.
// P stored fp8 unnormalized (exp(S - m_run), x256); U rescaled by alpha online;
// epilogue divides by 256*l_run. S never touches HBM.
__global__ __launch_bounds__(512) void flash(
    const unsigned char* __restrict__ Qg8,   // PH8 [8][2048][512]
    const unsigned char* __restrict__ Kg8,   // TH8 [8][2048][512]
    const unsigned char* __restrict__ Vg8,   // VT8 [8][512][2048]
    unsigned char* __restrict__ out8) {      // xadd [8][2048][512]
    __shared__ unsigned char Qs[64 * 512];
    __shared__ unsigned char Ks[2][128 * 128];
    __shared__ unsigned char Vs[512 * 128];
    __shared__ unsigned char Ps[64 * 128];
    __shared__ float smax[2][32][4];
    __shared__ float ssum[2][32][4];

    const int tid  = threadIdx.x;
    const int lane = tid & 63, wave = tid >> 6;
    const int m16  = lane & 15, quad = lane >> 4;
    const int lg   = wave >> 2;          // l-group (32 rows)
    const int mw   = wave & 3;           // m-group (S) / h-group (PV)
    const int z    = blockIdx.y;
    const int l0   = blockIdx.x << 6;

    const unsigned char* Qg = Qg8 + ((long)z * 2048 + l0) * 512;
    const unsigned char* Kg = Kg8 + (long)z * 2048 * 512;
    const unsigned char* Vg = Vg8 + (long)z * 512 * 2048;

    const int s8  = m16 & 7;
    const int cLo = ((quad ^ (s8 >> 1)) << 1) + (s8 & 1);
    const int offLo = cLo << 4, offHi = (cLo ^ 1) << 4;

    auto stageQ = [&]() {                // 64x512 once: 4 instrs, 2 rows each
#pragma unroll
        for (int i = 0; i < 4; ++i) {
            const int slot = wave * 4 + i;
            const int row  = slot * 2 + (lane >> 5);
            const int w5   = lane & 31;
            const int su   = (w5 & 24) | ((w5 & 7) ^ (row & 7));
            const unsigned char* gp = Qg + (long)row * 512 + (su << 4);
            __builtin_amdgcn_global_load_lds((glb_uint*)gp, (lds_uint*)&Qs[slot << 10], 16, 0, 0);
        }
    };
    auto stageK = [&](int t) {           // K-tile t: rows (t>>2)*128.., cols (t&3)*128
        const int c = t >> 2, ks = t & 3;
#pragma unroll
        for (int i = 0; i < 2; ++i) {
            const int slot = wave * 2 + i;
            const int row  = (slot << 3) + (lane >> 3);
            const int su   = (lane & 7) ^ (row & 7);
            const unsigned char* gp = Kg + (long)(c * 128 + row) * 512 + ks * 128 + (su << 4);
            __builtin_amdgcn_global_load_lds((glb_uint*)gp, (lds_uint*)&Ks[t & 1][slot << 10], 16, 0, 0);
        }
    };
    auto stageV = [&](int c) {           // V chunk: 512 h-rows x 128 m
#pragma unroll
        for (int i = 0; i < 8; ++i) {
            const int slot = wave * 8 + i;
            const int row  = (slot << 3) + (lane >> 3);
            const int su   = (lane & 7) ^ (row & 7);
            const unsigned char* gp = Vg + (long)row * 2048 + c * 128 + (su << 4);
            __builtin_amdgcn_global_load_lds((glb_uint*)gp, (lds_uint*)&Vs[slot << 10], 16, 0, 0);
        }
    };

    f32x4 U[2][8] = {};
    float m_run[2][4], l_run[2][4];
#pragma unroll
    for (int a = 0; a < 2; ++a)
#pragma unroll
        for (int b = 0; b < 4; ++b) { m_run[a][b] = -3.0e38f; l_run[a][b] = 0.0f; }

    union F8 { v8i v; int4 q[2]; };

    stageQ();
    stageK(0);

    for (int c = 0; c < 16; ++c) {
        f32x4 sacc[2][2] = {};
        // ---- S-chunk: 4 k-steps over C=512 ----
#pragma unroll
        for (int ks = 0; ks < 4; ++ks) {
            const int t = c * 4 + ks;
            if (t + 1 < 64) stageK(t + 1);   // 2 loads
            if (ks == 1) stageV(c);          // 8 loads, issued early (T14)
            // in-order vmcnt accounting: N = #loads issued after K(t)
            if (ks == 0) {
                asm volatile("s_waitcnt vmcnt(2)" ::: "memory");       // after K(t): K(t+1)
            } else if (ks == 3) {
                if (c == 15) asm volatile("s_waitcnt vmcnt(0)" ::: "memory");
                else         asm volatile("s_waitcnt vmcnt(2)" ::: "memory");  // K(t+1) only
            } else {
                asm volatile("s_waitcnt vmcnt(10)" ::: "memory");      // V(8)+K(t+1)(2)
            }
            asm volatile("s_barrier" ::: "memory");

            const unsigned char* Kb = Ks[t & 1];
            F8 aq[2], bk[2];
#pragma unroll
            for (int f = 0; f < 2; ++f) {
                const int l = lg * 32 + f * 16 + m16;
                aq[f].q[0] = *(const int4*)&Qs[l * 512 + ks * 128 + offLo];
                aq[f].q[1] = *(const int4*)&Qs[l * 512 + ks * 128 + offHi];
                const int m = mw * 32 + f * 16 + m16;
                bk[f].q[0] = *(const int4*)&Kb[(m << 7) + offLo];
                bk[f].q[1] = *(const int4*)&Kb[(m << 7) + offHi];
            }
#pragma unroll
            for (int fi = 0; fi < 2; ++fi)
#pragma unroll
                for (int fj = 0; fj < 2; ++fj)
                    sacc[fi][fj] = __builtin_amdgcn_mfma_scale_f32_16x16x128_f8f6f4(
                        aq[fi].v, bk[fj].v, sacc[fi][fj], 0, 0, 0, 127, 0, 127);

            asm volatile("s_waitcnt lgkmcnt(0)" ::: "memory");
            asm volatile("s_barrier" ::: "memory");
        }

        // ---- online softmax ----
        // S-frag elem (fi,fj,r): row = fi*16+quad*4+r, col = mw*32+fj*16+m16
        float pm[2][4];
#pragma unroll
        for (int fi = 0; fi < 2; ++fi)
#pragma unroll
            for (int r = 0; r < 4; ++r) {
                float v = fmaxf(sacc[fi][0][r], sacc[fi][1][r]);
#pragma unroll
                for (int off = 1; off < 16; off <<= 1) v = fmaxf(v, __shfl_xor(v, off));
                pm[fi][r] = v;
            }
        if (m16 == 0) {
#pragma unroll
            for (int fi = 0; fi < 2; ++fi)
#pragma unroll
                for (int r = 0; r < 4; ++r)
                    smax[lg][fi * 16 + quad * 4 + r][mw] = pm[fi][r];
        }
        asm volatile("s_waitcnt lgkmcnt(0)" ::: "memory");
        asm volatile("s_barrier" ::: "memory");

        float alpha[2][4], p[2][2][4];
#pragma unroll
        for (int fi = 0; fi < 2; ++fi)
#pragma unroll
            for (int r = 0; r < 4; ++r) {
                const int rr = fi * 16 + quad * 4 + r;
                float cm = fmaxf(fmaxf(smax[lg][rr][0], smax[lg][rr][1]),
                                 fmaxf(smax[lg][rr][2], smax[lg][rr][3]));
                const float mo = m_run[fi][r];
                const float mn = fmaxf(mo, cm);
                m_run[fi][r] = mn;
                alpha[fi][r] = __expf(mo - mn);
#pragma unroll
                for (int fj = 0; fj < 2; ++fj)
                    p[fi][fj][r] = __expf(sacc[fi][fj][r] - mn);
            }
#pragma unroll
        for (int fi = 0; fi < 2; ++fi)
#pragma unroll
            for (int fh = 0; fh < 8; ++fh)
#pragma unroll
                for (int r = 0; r < 4; ++r)
                    U[fi][fh][r] *= alpha[fi][r];
        float ps[2][4];
#pragma unroll
        for (int fi = 0; fi < 2; ++fi)
#pragma unroll
            for (int r = 0; r < 4; ++r) {
                float v = p[fi][0][r] + p[fi][1][r];
#pragma unroll
                for (int off = 1; off < 16; off <<= 1) v += __shfl_xor(v, off);
                ps[fi][r] = v;
            }
        if (m16 == 0) {
#pragma unroll
            for (int fi = 0; fi < 2; ++fi)
#pragma unroll
                for (int r = 0; r < 4; ++r)
                    ssum[lg][fi * 16 + quad * 4 + r][mw] = ps[fi][r];
        }
        // P bytes -> LDS with the unit-XOR layout (storage unit s holds true s^(l&7))
#pragma unroll
        for (int fi = 0; fi < 2; ++fi)
#pragma unroll
            for (int r = 0; r < 4; ++r) {
                const int l = lg * 32 + fi * 16 + quad * 4 + r;
#pragma unroll
                for (int fj = 0; fj < 2; ++fj) {
                    const int m = mw * 32 + fj * 16 + m16;
                    Ps[(l << 7) + ((((m >> 4) ^ (l & 7)) << 4) | (m & 15))] =
                        f2fp8(p[fi][fj][r] * 256.0f);
                }
            }
        asm volatile("s_waitcnt vmcnt(2) lgkmcnt(0)" ::: "memory");  // V landed; P/ssum visible
        asm volatile("s_barrier" ::: "memory");

#pragma unroll
        for (int fi = 0; fi < 2; ++fi)
#pragma unroll
            for (int r = 0; r < 4; ++r) {
                const int rr = fi * 16 + quad * 4 + r;
                l_run[fi][r] = l_run[fi][r] * alpha[fi][r] +
                               ssum[lg][rr][0] + ssum[lg][rr][1] +
                               ssum[lg][rr][2] + ssum[lg][rr][3];
            }

        // ---- PV: U += P(64x128) @ V^T(512x128 rows h) ----
        F8 pa[2];
#pragma unroll
        for (int f = 0; f < 2; ++f) {
            const int l = lg * 32 + f * 16 + m16;
            pa[f].q[0] = *(const int4*)&Ps[(l << 7) + offLo];
            pa[f].q[1] = *(const int4*)&Ps[(l << 7) + offHi];
        }
#pragma unroll
        for (int fh = 0; fh < 8; ++fh) {
            F8 vb;
            const int h = mw * 128 + fh * 16 + m16;
            vb.q[0] = *(const int4*)&Vs[(h << 7) + offLo];
            vb.q[1] = *(const int4*)&Vs[(h << 7) + offHi];
#pragma unroll
            for (int fi = 0; fi < 2; ++fi)
                U[fi][fh] = __builtin_amdgcn_mfma_scale_f32_16x16x128_f8f6f4(
                    pa[fi].v, vb.v, U[fi][fh], 0, 0, 0, 127, 0, 127);
        }
        asm volatile("s_waitcnt lgkmcnt(0)" ::: "memory");
        asm volatile("s_barrier" ::: "memory");
    }

    // ---- epilogue: normalize, fp8 store ----
#pragma unroll
    for (int fi = 0; fi < 2; ++fi)
#pragma unroll
        for (int r = 0; r < 4; ++r) {
            const float inv = 1.0f / (256.0f * l_run[fi][r]);
            const long row = (long)z * 2048 + l0 + lg * 32 + fi * 16 + quad * 4 + r;
#pragma unroll
            for (int fh = 0; fh < 8; ++fh) {
                const int h = mw * 128 + fh * 16 + m16;
                out8[row * 512 + h] = f2fp8(U[fi][fh][r] * inv);
            }
        }
}

// ---------- launch ----------
extern "C" void kernel_launch(void* const* d_in, const int* in_sizes, int n_in,
                              void* d_out, int out_size, void* d_ws, size_t ws_size,
                              hipStream_t stream) {
    const float* x       = (const float*)d_in[0];
    const float* theta_w = (const float*)d_in[1];
    const float* theta_b = (const float*)d_in[2];
    const float* phi_w   = (const float*)d_in[3];
    const float* phi_b   = (const float*)d_in[4];
    const float* psi_w   = (const float*)d_in[5];
    const float* psi_b   = (const float*)d_in[6];
    const float* r1_w    = (const float*)d_in[7];
    const float* r1_b    = (const float*)d_in[8];
    const float* r2_w    = (const float*)d_in[9];
    const float* r2_b    = (const float*)d_in[10];
    float* out = (float*)d_out;

    constexpr int  N = 8, L = 2048, C = 512, H = 512, CH = 256;
    constexpr long NL = (long)N * L;  // 16384

    char* p = (char*)d_ws;
    auto alloc = [&](size_t bytes) { void* q = (void*)p; p += bytes; return q; };
    unsigned char*  xb8    = (unsigned char*)alloc(NL * C);            //  8 MB
    unsigned char*  TH8    = (unsigned char*)alloc(NL * H);            //  8 MB
    unsigned char*  PH8    = (unsigned char*)alloc(NL * H);            //  8 MB
    unsigned char*  VT8    = (unsigned char*)alloc((long)N * H * L);   //  8 MB
    unsigned char*  xadd8  = (unsigned char*)alloc(NL * H);            //  8 MB
    unsigned char*  h18    = (unsigned char*)alloc(NL * CH);           //  4 MB
    unsigned char*  wCat8T = (unsigned char*)alloc((long)1536 * 512);
    unsigned char*  r1T8   = (unsigned char*)alloc((long)H * CH);
    unsigned char*  r2T8   = (unsigned char*)alloc((long)CH * C);
    float*          bCat   = (float*)alloc(1536 * 4 + 256);

    // 1. prep
    prep<<<12294, 256, 0, stream>>>(x, theta_w, phi_w, psi_w, r1_w, r2_w,
                                    theta_b, phi_b, psi_b, xb8, wCat8T, r1T8, r2T8, bCat);

    // 2. merged fp8 projections -> TH8, PH8, VT8 (V^T via packed dword stores)
    gemm_fp8<0><<<dim3(NL / 128, 1536 / 128, 1), 256, 0, stream>>>(
        xb8, wCat8T, bCat, nullptr, TH8, PH8, VT8, nullptr,
        C, C, C, 0, 0, 0, 0);

    // 3-5. fused attention: S -> online softmax -> P@V, all in one kernel
    flash<<<dim3(L / 64, N, 1), 512, 0, stream>>>(PH8, TH8, VT8, xadd8);

    // 6. h1 = leaky(x_add @ r1 + b) -> fp8
    gemm_fp8<3><<<dim3(NL / 128, CH / 128, 1), 256, 0, stream>>>(
        xadd8, r1T8, r1_b, nullptr, h18, nullptr, nullptr, nullptr,
        H, H, H, CH, 0, 0, 0);

    // 7. out = x + tanh(h1 @ r2 + b) -> fp32
    gemm_fp8<4><<<dim3(NL / 128, C / 128, 1), 256, 0, stream>>>(
        h18, r2T8, r2_b, x, nullptr, nullptr, nullptr, out,
        CH, CH, CH, C, 0, 0, 0);
}